// Round 1
// baseline (1097.040 us; speedup 1.0000x reference)
//
#include <hip/hip_runtime.h>
#include <hip/hip_bf16.h>
#include <math.h>

#define NB 32          // graphs
#define N_PER 1000
#define TOTALN 32000
#define NE 512000
#define HID 128
#define Dh 64
#define NH 3
#define EPSV 1e-6f
#define NCH 8          // n's per k_w1 block

__device__ __forceinline__ float softplusf(float x) {
    // stable log1p(exp(x)) = max(x,0) + log1p(exp(-|x|))
    return fmaxf(x, 0.0f) + log1pf(expf(-fabsf(x)));
}

__global__ __launch_bounds__(256) void k_init_deg(float* deg) {
    int i = blockIdx.x * 256 + threadIdx.x;
    if (i < TOTALN) deg[i] = 1.0f;   // self loop
}

__global__ __launch_bounds__(256) void k_deg(const int* __restrict__ ei, float* deg) {
    int e = blockIdx.x * 256 + threadIdx.x;
    if (e < NE) atomicAdd(&deg[ei[NE + e]], 1.0f);
}

__global__ __launch_bounds__(256) void k_rsqrt(float* d) {
    int i = blockIdx.x * 256 + threadIdx.x;
    if (i < TOTALN) d[i] = rsqrtf(d[i]);
}

// Y[rows x 128] = X[rows x 128] @ W[128 x 128]; 64 rows per block
__global__ __launch_bounds__(256) void k_mm128(const float* __restrict__ X,
                                               const float* __restrict__ W,
                                               float* __restrict__ Y) {
    __shared__ float xs[64][128];
    __shared__ float ws[32][128];
    int tid = threadIdx.x;
    int row0 = blockIdx.x * 64;
    int c = tid & 127, rp = tid >> 7;
    for (int i = 0; i < 32; ++i) {
        int idx = tid + i * 256;
        xs[idx >> 7][idx & 127] = X[(row0 + (idx >> 7)) * 128 + (idx & 127)];
    }
    float acc[32];
#pragma unroll
    for (int i = 0; i < 32; ++i) acc[i] = 0.f;
    for (int kc = 0; kc < 4; ++kc) {
        __syncthreads();
        for (int i = 0; i < 16; ++i) {
            int idx = tid + i * 256;
            ws[idx >> 7][idx & 127] = W[(kc * 32 + (idx >> 7)) * 128 + (idx & 127)];
        }
        __syncthreads();
#pragma unroll 4
        for (int k = 0; k < 32; ++k) {
            float w = ws[k][c];
#pragma unroll
            for (int i = 0; i < 32; ++i)
                acc[i] += xs[rp * 32 + i][kc * 32 + k] * w;
        }
    }
#pragma unroll
    for (int i = 0; i < 32; ++i)
        Y[(row0 + rp * 32 + i) * 128 + c] = acc[i];
}

// out[v] = in[v] * dinv[v]^2  (self-loop message; also zero-initializes out)
__global__ __launch_bounds__(256) void k_selfloop(const float* __restrict__ in,
                                                  float* __restrict__ out,
                                                  const float* __restrict__ dinv) {
    int i = blockIdx.x * 256 + threadIdx.x;
    int v = i >> 7;
    float dv = dinv[v];
    out[i] = in[i] * dv * dv;
}

// 2 edges per block, 128 lanes per edge
__global__ __launch_bounds__(256) void k_edges(const float* __restrict__ feat,
                                               float* __restrict__ out,
                                               const int* __restrict__ ei,
                                               const float* __restrict__ dinv) {
    int e = blockIdx.x * 2 + (threadIdx.x >> 7);
    int c = threadIdx.x & 127;
    int s = ei[e], d = ei[NE + e];
    float nrm = dinv[s] * dinv[d];
    atomicAdd(&out[d * 128 + c], feat[s * 128 + c] * nrm);
}

__global__ __launch_bounds__(256) void k_biasrelu(float* __restrict__ a,
                                                  const float* __restrict__ b) {
    int i = blockIdx.x * 256 + threadIdx.x;
    a[i] = fmaxf(a[i] + b[i & 127], 0.f);
}

// mean pool per graph + layer-3 bias fold
__global__ __launch_bounds__(256) void k_pool(const float* __restrict__ A,
                                              const float* __restrict__ bias,
                                              float* __restrict__ hg) {
    __shared__ float sh[256];
    int b = blockIdx.x;
    int c = threadIdx.x & 127, half = threadIdx.x >> 7;
    float acc = 0.f;
    for (int n = half; n < N_PER; n += 2)
        acc += A[(b * N_PER + n) * 128 + c];
    sh[threadIdx.x] = acc;
    __syncthreads();
    if (threadIdx.x < 128)
        hg[b * 128 + c] = (sh[c] + sh[128 + c]) * (1.0f / N_PER) + bias[c];
}

// block = (head h, chunk of 8 n's); streams Wg1 once; partials p1[chunk][h][b][d]
__global__ __launch_bounds__(256) void k_w1(const float* __restrict__ hg,
                                            const float* __restrict__ Wg1,
                                            const float* __restrict__ bg1,
                                            const float* __restrict__ actions,
                                            float* __restrict__ p1) {
    __shared__ float hgs[32][128];
    __shared__ float wt[128][64];
    __shared__ float act[32];
    int h = blockIdx.x / 125;
    int chunk = blockIdx.x % 125;
    int tid = threadIdx.x;
    for (int i = 0; i < 16; ++i) {
        int idx = tid + i * 256;
        hgs[idx >> 7][idx & 127] = hg[idx];
    }
    int d = tid & 63, bq = tid >> 6;
    float acc[8];
#pragma unroll
    for (int i = 0; i < 8; ++i) acc[i] = 0.f;
    for (int j = 0; j < NCH; ++j) {
        int n = chunk * NCH + j;
        long base = (long)(h * N_PER + n) * Dh;
        __syncthreads();
        for (int i = 0; i < 32; ++i) {
            int idx = tid + i * 256;
            wt[idx >> 6][idx & 63] = Wg1[(long)(idx >> 6) * (NH * N_PER * Dh) + base + (idx & 63)];
        }
        if (tid < 32) act[tid] = actions[tid * N_PER + n];
        __syncthreads();
        float bgv = bg1[base + d];
        float dot[8];
#pragma unroll
        for (int bi = 0; bi < 8; ++bi) dot[bi] = 0.f;
        for (int k = 0; k < 128; ++k) {
            float w = wt[k][d];
#pragma unroll
            for (int bi = 0; bi < 8; ++bi)
                dot[bi] += hgs[bq * 8 + bi][k] * w;
        }
#pragma unroll
        for (int bi = 0; bi < 8; ++bi)
            acc[bi] += act[bq * 8 + bi] * softplusf(dot[bi] + bgv);
    }
    float* po = p1 + (long)(chunk * NH + h) * (32 * 64);
#pragma unroll
    for (int bi = 0; bi < 8; ++bi)
        po[(bq * 8 + bi) * 64 + d] = acc[bi];
}

__global__ __launch_bounds__(256) void k_red1(const float* __restrict__ p1,
                                              float* __restrict__ h1) {
    int o = blockIdx.x * 256 + threadIdx.x;  // b*192 + h*64 + d
    if (o >= 32 * 192) return;
    int bh = o >> 6;
    int h = bh % 3, b = bh / 3;
    int d = o & 63;
    float s = 0.f;
    for (int ch = 0; ch < 125; ++ch)
        s += p1[(ch * 3 + h) * 2048 + b * 64 + d];
    h1[o] = sqrtf(fmaxf(s, 0.f) + EPSV);   // SafeSqrt
}

// block = (h*64+d); writes p2[hd][b][e]
__global__ __launch_bounds__(256) void k_w2(const float* __restrict__ hg,
                                            const float* __restrict__ Wg2,
                                            const float* __restrict__ bg2,
                                            const float* __restrict__ h1,
                                            float* __restrict__ p2) {
    __shared__ float hgs[32][128];
    __shared__ float wt[128][64];
    __shared__ float h1s[32];
    int hd = blockIdx.x;  // h*64 + d
    int tid = threadIdx.x;
    for (int i = 0; i < 16; ++i) {
        int idx = tid + i * 256;
        hgs[idx >> 7][idx & 127] = hg[idx];
    }
    long base = (long)hd * 64;
    for (int i = 0; i < 32; ++i) {
        int idx = tid + i * 256;
        wt[idx >> 6][idx & 63] = Wg2[(long)(idx >> 6) * (NH * Dh * Dh) + base + (idx & 63)];
    }
    int h = hd >> 6, d = hd & 63;
    if (tid < 32) h1s[tid] = h1[tid * (NH * Dh) + h * Dh + d];
    __syncthreads();
    int e = tid & 63, bq = tid >> 6;
    float bgv = bg2[base + e];
    float dot[8];
#pragma unroll
    for (int bi = 0; bi < 8; ++bi) dot[bi] = 0.f;
    for (int k = 0; k < 128; ++k) {
        float w = wt[k][e];
#pragma unroll
        for (int bi = 0; bi < 8; ++bi)
            dot[bi] += hgs[bq * 8 + bi][k] * w;
    }
    float* po = p2 + (long)hd * (32 * 64);
#pragma unroll
    for (int bi = 0; bi < 8; ++bi) {
        int b = bq * 8 + bi;
        po[b * 64 + e] = softplusf(dot[bi] + bgv) * h1s[b];
    }
}

__global__ __launch_bounds__(256) void k_red2(const float* __restrict__ p2,
                                              float* __restrict__ h2) {
    int o = blockIdx.x * 256 + threadIdx.x;  // b*192 + h*64 + e
    if (o >= 32 * 192) return;
    int bh = o >> 6;
    int h = bh % 3, b = bh / 3;
    int e = o & 63;
    float s = 0.f;
    for (int d = 0; d < 64; ++d)
        s += p2[(h * 64 + d) * 2048 + b * 64 + e];
    h2[o] = log1pf(fmaxf(s, 0.f));   // SafeLog
}

__global__ __launch_bounds__(192) void k_out(const float* __restrict__ hg,
                                             const float* __restrict__ Wg3,
                                             const float* __restrict__ bg3,
                                             const float* __restrict__ h2,
                                             float* __restrict__ out) {
    __shared__ float hgb[128];
    __shared__ float hres[NH];
    int b = blockIdx.x, tid = threadIdx.x;
    if (tid < 128) hgb[tid] = hg[b * 128 + tid];
    __syncthreads();
    int h = tid / 64, e = tid & 63;
    int c = h * 64 + e;
    float dot = 0.f;
    for (int k = 0; k < 128; ++k)
        dot += hgb[k] * Wg3[k * (NH * Dh) + c];
    float v = softplusf(dot + bg3[c]) * h2[b * 192 + c];
    for (int off = 32; off; off >>= 1)
        v += __shfl_down(v, off, 64);
    if (e == 0) hres[h] = v;
    __syncthreads();
    if (tid == 0) out[b] = fminf(fminf(hres[0], hres[1]), hres[2]);
}

extern "C" void kernel_launch(void* const* d_in, const int* in_sizes, int n_in,
                              void* d_out, int out_size, void* d_ws, size_t ws_size,
                              hipStream_t stream) {
    const float* x   = (const float*)d_in[0];
    const int*   ei  = (const int*)d_in[1];
    // d_in[2] batch_index: known structure (repeat(arange(32),1000)) — unused
    const float* act = (const float*)d_in[3];
    const float* Wc1 = (const float*)d_in[4];
    const float* bc1 = (const float*)d_in[5];
    const float* Wc2 = (const float*)d_in[6];
    const float* bc2 = (const float*)d_in[7];
    const float* Wc3 = (const float*)d_in[8];
    const float* bc3 = (const float*)d_in[9];
    const float* Wg1 = (const float*)d_in[10];
    const float* bg1 = (const float*)d_in[11];
    const float* Wg2 = (const float*)d_in[12];
    const float* bg2 = (const float*)d_in[13];
    const float* Wg3 = (const float*)d_in[14];
    const float* bg3 = (const float*)d_in[15];
    float* out = (float*)d_out;

    float* ws   = (float*)d_ws;
    float* dinv = ws;                               // 32000
    float* bufA = dinv + TOTALN;                    // 4.096M
    float* bufB = bufA + (long)TOTALN * 128;        // 4.096M
    float* hg   = bufB + (long)TOTALN * 128;        // 4096
    float* h1   = hg + 32 * 128;                    // 6144
    float* h2   = h1 + 32 * 192;                    // 6144
    float* p1   = h2 + 32 * 192;                    // 768000
    float* p2   = p1 + 125 * 3 * 2048;              // 393216  (total ~37.6 MB)

    k_init_deg<<<(TOTALN + 255) / 256, 256, 0, stream>>>(dinv);
    k_deg<<<NE / 256, 256, 0, stream>>>(ei, dinv);
    k_rsqrt<<<(TOTALN + 255) / 256, 256, 0, stream>>>(dinv);

    // layer 1
    k_mm128<<<500, 256, 0, stream>>>(x, Wc1, bufB);
    k_selfloop<<<TOTALN * 128 / 256, 256, 0, stream>>>(bufB, bufA, dinv);
    k_edges<<<NE / 2, 256, 0, stream>>>(bufB, bufA, ei, dinv);
    k_biasrelu<<<TOTALN * 128 / 256, 256, 0, stream>>>(bufA, bc1);
    // layer 2
    k_mm128<<<500, 256, 0, stream>>>(bufA, Wc2, bufB);
    k_selfloop<<<TOTALN * 128 / 256, 256, 0, stream>>>(bufB, bufA, dinv);
    k_edges<<<NE / 2, 256, 0, stream>>>(bufB, bufA, ei, dinv);
    k_biasrelu<<<TOTALN * 128 / 256, 256, 0, stream>>>(bufA, bc2);
    // layer 3 (no relu; bias folded into pool)
    k_mm128<<<500, 256, 0, stream>>>(bufA, Wc3, bufB);
    k_selfloop<<<TOTALN * 128 / 256, 256, 0, stream>>>(bufB, bufA, dinv);
    k_edges<<<NE / 2, 256, 0, stream>>>(bufB, bufA, ei, dinv);
    k_pool<<<NB, 256, 0, stream>>>(bufA, bc3, hg);

    // hypernetwork + compute_q
    k_w1<<<NH * (N_PER / NCH), 256, 0, stream>>>(hg, Wg1, bg1, act, p1);
    k_red1<<<24, 256, 0, stream>>>(p1, h1);
    k_w2<<<NH * Dh, 256, 0, stream>>>(hg, Wg2, bg2, h1, p2);
    k_red2<<<24, 256, 0, stream>>>(p2, h2);
    k_out<<<NB, 192, 0, stream>>>(hg, Wg3, bg3, h2, out);
}

// Round 2
// 617.758 us; speedup vs baseline: 1.7758x; 1.7758x over previous
//
#include <hip/hip_runtime.h>
#include <hip/hip_bf16.h>
#include <math.h>

#define NB 32          // graphs
#define N_PER 1000
#define TOTALN 32000
#define NE 512000
#define HID 128
#define Dh 64
#define NH 3
#define EPSV 1e-6f
#define NCH 8          // n's per k_w1 block

__device__ __forceinline__ float softplusf(float x) {
    return fmaxf(x, 0.0f) + log1pf(expf(-fabsf(x)));
}

__global__ __launch_bounds__(256) void k_init_deg(float* deg) {
    int i = blockIdx.x * 256 + threadIdx.x;
    if (i < TOTALN) deg[i] = 1.0f;   // self loop
}

__global__ __launch_bounds__(256) void k_deg(const int* __restrict__ ei, float* deg) {
    int e = blockIdx.x * 256 + threadIdx.x;
    if (e < NE) atomicAdd(&deg[ei[NE + e]], 1.0f);
}

// dinv = rsqrt(deg); cnt = (int)deg - 1 (edges only, self-loop excluded)
__global__ __launch_bounds__(256) void k_prep(float* __restrict__ d, int* __restrict__ cnt) {
    int i = blockIdx.x * 256 + threadIdx.x;
    if (i < TOTALN) {
        float v = d[i];
        cnt[i] = (int)v - 1;
        d[i] = rsqrtf(v);
    }
}

// exclusive scan of cnt[32000] -> rowptr; 125 blocks x 256
__global__ __launch_bounds__(256) void k_scan_block(const int* __restrict__ cnt,
                                                    int* __restrict__ rowptr,
                                                    int* __restrict__ bsum) {
    __shared__ int sh[256];
    int t = threadIdx.x;
    int i = blockIdx.x * 256 + t;
    int v = cnt[i];
    sh[t] = v;
    __syncthreads();
    for (int off = 1; off < 256; off <<= 1) {
        int add = (t >= off) ? sh[t - off] : 0;
        __syncthreads();
        sh[t] += add;
        __syncthreads();
    }
    rowptr[i] = sh[t] - v;   // exclusive within block
    if (t == 255) bsum[blockIdx.x] = sh[255];
}

__global__ void k_scan_tot(int* __restrict__ bsum) {
    if (threadIdx.x == 0) {
        int run = 0;
        for (int i = 0; i < 125; ++i) { int t = bsum[i]; bsum[i] = run; run += t; }
    }
}

__global__ __launch_bounds__(256) void k_scan_add(int* __restrict__ rowptr,
                                                  const int* __restrict__ bsum,
                                                  int* __restrict__ cursor) {
    int i = blockIdx.x * 256 + threadIdx.x;
    int v = rowptr[i] + bsum[blockIdx.x];
    rowptr[i] = v;
    cursor[i] = v;
    if (i == 0) rowptr[TOTALN] = NE;
}

__global__ __launch_bounds__(256) void k_fill(const int* __restrict__ ei,
                                              const float* __restrict__ dinv,
                                              int* __restrict__ cursor,
                                              int* __restrict__ csr_src,
                                              float* __restrict__ csr_w) {
    int e = blockIdx.x * 256 + threadIdx.x;
    if (e < NE) {
        int s = ei[e], d = ei[NE + e];
        int pos = atomicAdd(&cursor[d], 1);
        csr_src[pos] = s;
        csr_w[pos] = dinv[s] * dinv[d];
    }
}

// Y[rows x 128] = X[rows x 128] @ W[128 x 128]; 64 rows per block
__global__ __launch_bounds__(256) void k_mm128(const float* __restrict__ X,
                                               const float* __restrict__ W,
                                               float* __restrict__ Y) {
    __shared__ float xs[64][128];
    __shared__ float ws[32][128];
    int tid = threadIdx.x;
    int row0 = blockIdx.x * 64;
    int c = tid & 127, rp = tid >> 7;
    for (int i = 0; i < 32; ++i) {
        int idx = tid + i * 256;
        xs[idx >> 7][idx & 127] = X[(row0 + (idx >> 7)) * 128 + (idx & 127)];
    }
    float acc[32];
#pragma unroll
    for (int i = 0; i < 32; ++i) acc[i] = 0.f;
    for (int kc = 0; kc < 4; ++kc) {
        __syncthreads();
        for (int i = 0; i < 16; ++i) {
            int idx = tid + i * 256;
            ws[idx >> 7][idx & 127] = W[(kc * 32 + (idx >> 7)) * 128 + (idx & 127)];
        }
        __syncthreads();
#pragma unroll 4
        for (int k = 0; k < 32; ++k) {
            float w = ws[k][c];
#pragma unroll
            for (int i = 0; i < 32; ++i)
                acc[i] += xs[rp * 32 + i][kc * 32 + k] * w;
        }
    }
#pragma unroll
    for (int i = 0; i < 32; ++i)
        Y[(row0 + rp * 32 + i) * 128 + c] = acc[i];
}

// CSR gather: 1 wave per node, float2 per lane. MODE 0: +bias,relu ; MODE 1: plain
template<int MODE>
__global__ __launch_bounds__(256) void k_gather(const float* __restrict__ feat,
                                                float* __restrict__ out,
                                                const int* __restrict__ rowptr,
                                                const int* __restrict__ csr_src,
                                                const float* __restrict__ csr_w,
                                                const float* __restrict__ dinv,
                                                const float* __restrict__ bias) {
    int wid = threadIdx.x >> 6, lane = threadIdx.x & 63;
    int v = blockIdx.x * 4 + wid;
    const float2* f2 = (const float2*)feat;
    float dv = dinv[v];
    float2 self = f2[v * 64 + lane];
    float acc0 = self.x * dv * dv, acc1 = self.y * dv * dv;
    int e1 = rowptr[v + 1];
    for (int e = rowptr[v]; e < e1; ++e) {
        int s = csr_src[e];
        float w = csr_w[e];
        float2 f = f2[s * 64 + lane];
        acc0 += f.x * w;
        acc1 += f.y * w;
    }
    if (MODE == 0) {
        int c = lane * 2;
        acc0 = fmaxf(acc0 + bias[c], 0.f);
        acc1 = fmaxf(acc1 + bias[c + 1], 0.f);
    }
    ((float2*)out)[v * 64 + lane] = make_float2(acc0, acc1);
}

// mean pool per graph + layer-3 bias fold
__global__ __launch_bounds__(256) void k_pool(const float* __restrict__ A,
                                              const float* __restrict__ bias,
                                              float* __restrict__ hg) {
    __shared__ float sh[256];
    int b = blockIdx.x;
    int c = threadIdx.x & 127, half = threadIdx.x >> 7;
    float acc = 0.f;
    for (int n = half; n < N_PER; n += 2)
        acc += A[(b * N_PER + n) * 128 + c];
    sh[threadIdx.x] = acc;
    __syncthreads();
    if (threadIdx.x < 128)
        hg[b * 128 + c] = (sh[c] + sh[128 + c]) * (1.0f / N_PER) + bias[c];
}

// block = (head h, chunk of 8 n's); streams Wg1 once; partials p1[chunk][h][b][d]
__global__ __launch_bounds__(256) void k_w1(const float* __restrict__ hg,
                                            const float* __restrict__ Wg1,
                                            const float* __restrict__ bg1,
                                            const float* __restrict__ actions,
                                            float* __restrict__ p1) {
    __shared__ float hgs[32][128];
    __shared__ float wt[128][64];
    __shared__ float act[32];
    int h = blockIdx.x / 125;
    int chunk = blockIdx.x % 125;
    int tid = threadIdx.x;
    for (int i = 0; i < 16; ++i) {
        int idx = tid + i * 256;
        hgs[idx >> 7][idx & 127] = hg[idx];
    }
    int d = tid & 63, bq = tid >> 6;
    float acc[8];
#pragma unroll
    for (int i = 0; i < 8; ++i) acc[i] = 0.f;
    for (int j = 0; j < NCH; ++j) {
        int n = chunk * NCH + j;
        long base = (long)(h * N_PER + n) * Dh;
        __syncthreads();
        for (int i = 0; i < 32; ++i) {
            int idx = tid + i * 256;
            wt[idx >> 6][idx & 63] = Wg1[(long)(idx >> 6) * (NH * N_PER * Dh) + base + (idx & 63)];
        }
        if (tid < 32) act[tid] = actions[tid * N_PER + n];
        __syncthreads();
        float bgv = bg1[base + d];
        float dot[8];
#pragma unroll
        for (int bi = 0; bi < 8; ++bi) dot[bi] = 0.f;
        for (int k = 0; k < 128; ++k) {
            float w = wt[k][d];
#pragma unroll
            for (int bi = 0; bi < 8; ++bi)
                dot[bi] += hgs[bq * 8 + bi][k] * w;
        }
#pragma unroll
        for (int bi = 0; bi < 8; ++bi)
            acc[bi] += act[bq * 8 + bi] * softplusf(dot[bi] + bgv);
    }
    float* po = p1 + (long)(chunk * NH + h) * (32 * 64);
#pragma unroll
    for (int bi = 0; bi < 8; ++bi)
        po[(bq * 8 + bi) * 64 + d] = acc[bi];
}

__global__ __launch_bounds__(256) void k_red1(const float* __restrict__ p1,
                                              float* __restrict__ h1) {
    int o = blockIdx.x * 256 + threadIdx.x;  // b*192 + h*64 + d
    if (o >= 32 * 192) return;
    int bh = o >> 6;
    int h = bh % 3, b = bh / 3;
    int d = o & 63;
    float s = 0.f;
    for (int ch = 0; ch < 125; ++ch)
        s += p1[(ch * 3 + h) * 2048 + b * 64 + d];
    h1[o] = sqrtf(fmaxf(s, 0.f) + EPSV);   // SafeSqrt
}

// block = (h*64+d); writes p2[hd][b][e]
__global__ __launch_bounds__(256) void k_w2(const float* __restrict__ hg,
                                            const float* __restrict__ Wg2,
                                            const float* __restrict__ bg2,
                                            const float* __restrict__ h1,
                                            float* __restrict__ p2) {
    __shared__ float hgs[32][128];
    __shared__ float wt[128][64];
    __shared__ float h1s[32];
    int hd = blockIdx.x;  // h*64 + d
    int tid = threadIdx.x;
    for (int i = 0; i < 16; ++i) {
        int idx = tid + i * 256;
        hgs[idx >> 7][idx & 127] = hg[idx];
    }
    long base = (long)hd * 64;
    for (int i = 0; i < 32; ++i) {
        int idx = tid + i * 256;
        wt[idx >> 6][idx & 63] = Wg2[(long)(idx >> 6) * (NH * Dh * Dh) + base + (idx & 63)];
    }
    int h = hd >> 6, d = hd & 63;
    if (tid < 32) h1s[tid] = h1[tid * (NH * Dh) + h * Dh + d];
    __syncthreads();
    int e = tid & 63, bq = tid >> 6;
    float bgv = bg2[base + e];
    float dot[8];
#pragma unroll
    for (int bi = 0; bi < 8; ++bi) dot[bi] = 0.f;
    for (int k = 0; k < 128; ++k) {
        float w = wt[k][e];
#pragma unroll
        for (int bi = 0; bi < 8; ++bi)
            dot[bi] += hgs[bq * 8 + bi][k] * w;
    }
    float* po = p2 + (long)hd * (32 * 64);
#pragma unroll
    for (int bi = 0; bi < 8; ++bi) {
        int b = bq * 8 + bi;
        po[b * 64 + e] = softplusf(dot[bi] + bgv) * h1s[b];
    }
}

__global__ __launch_bounds__(256) void k_red2(const float* __restrict__ p2,
                                              float* __restrict__ h2) {
    int o = blockIdx.x * 256 + threadIdx.x;  // b*192 + h*64 + e
    if (o >= 32 * 192) return;
    int bh = o >> 6;
    int h = bh % 3, b = bh / 3;
    int e = o & 63;
    float s = 0.f;
    for (int d = 0; d < 64; ++d)
        s += p2[(h * 64 + d) * 2048 + b * 64 + e];
    h2[o] = log1pf(fmaxf(s, 0.f));   // SafeLog
}

__global__ __launch_bounds__(192) void k_out(const float* __restrict__ hg,
                                             const float* __restrict__ Wg3,
                                             const float* __restrict__ bg3,
                                             const float* __restrict__ h2,
                                             float* __restrict__ out) {
    __shared__ float hgb[128];
    __shared__ float hres[NH];
    int b = blockIdx.x, tid = threadIdx.x;
    if (tid < 128) hgb[tid] = hg[b * 128 + tid];
    __syncthreads();
    int h = tid / 64, e = tid & 63;
    int c = h * 64 + e;
    float dot = 0.f;
    for (int k = 0; k < 128; ++k)
        dot += hgb[k] * Wg3[k * (NH * Dh) + c];
    float v = softplusf(dot + bg3[c]) * h2[b * 192 + c];
    for (int off = 32; off; off >>= 1)
        v += __shfl_down(v, off, 64);
    if (e == 0) hres[h] = v;
    __syncthreads();
    if (tid == 0) out[b] = fminf(fminf(hres[0], hres[1]), hres[2]);
}

extern "C" void kernel_launch(void* const* d_in, const int* in_sizes, int n_in,
                              void* d_out, int out_size, void* d_ws, size_t ws_size,
                              hipStream_t stream) {
    const float* x   = (const float*)d_in[0];
    const int*   ei  = (const int*)d_in[1];
    const float* act = (const float*)d_in[3];
    const float* Wc1 = (const float*)d_in[4];
    const float* bc1 = (const float*)d_in[5];
    const float* Wc2 = (const float*)d_in[6];
    const float* bc2 = (const float*)d_in[7];
    const float* Wc3 = (const float*)d_in[8];
    const float* bc3 = (const float*)d_in[9];
    const float* Wg1 = (const float*)d_in[10];
    const float* bg1 = (const float*)d_in[11];
    const float* Wg2 = (const float*)d_in[12];
    const float* bg2 = (const float*)d_in[13];
    const float* Wg3 = (const float*)d_in[14];
    const float* bg3 = (const float*)d_in[15];
    float* out = (float*)d_out;

    float* ws   = (float*)d_ws;
    float* dinv = ws;                               // 32000
    float* bufA = dinv + TOTALN;                    // 4.096M
    float* bufB = bufA + (long)TOTALN * 128;        // 4.096M
    float* hg   = bufB + (long)TOTALN * 128;        // 4096
    float* h1   = hg + 32 * 128;                    // 6144
    float* h2   = h1 + 32 * 192;                    // 6144
    float* p1   = h2 + 32 * 192;                    // 768000
    float* p2   = p1 + 125 * 3 * 2048;              // 393216
    float* csr_w = p2 + 3 * 64 * 2048;              // 512000
    int* cnt    = (int*)(csr_w + NE);               // 32000
    int* rowptr = cnt + TOTALN;                     // 32001
    int* cursor = rowptr + TOTALN + 1;              // 32000
    int* bsum   = cursor + TOTALN;                  // 128
    int* csr_src= bsum + 128;                       // 512000  (~44 MB total)

    // degree + norm + CSR build
    k_init_deg<<<(TOTALN + 255) / 256, 256, 0, stream>>>(dinv);
    k_deg<<<NE / 256, 256, 0, stream>>>(ei, dinv);
    k_prep<<<(TOTALN + 255) / 256, 256, 0, stream>>>(dinv, cnt);
    k_scan_block<<<125, 256, 0, stream>>>(cnt, rowptr, bsum);
    k_scan_tot<<<1, 64, 0, stream>>>(bsum);
    k_scan_add<<<125, 256, 0, stream>>>(rowptr, bsum, cursor);
    k_fill<<<NE / 256, 256, 0, stream>>>(ei, dinv, cursor, csr_src, csr_w);

    // layer 1
    k_mm128<<<500, 256, 0, stream>>>(x, Wc1, bufB);
    k_gather<0><<<TOTALN / 4, 256, 0, stream>>>(bufB, bufA, rowptr, csr_src, csr_w, dinv, bc1);
    // layer 2
    k_mm128<<<500, 256, 0, stream>>>(bufA, Wc2, bufB);
    k_gather<0><<<TOTALN / 4, 256, 0, stream>>>(bufB, bufA, rowptr, csr_src, csr_w, dinv, bc2);
    // layer 3 (no relu; bias folded into pool)
    k_mm128<<<500, 256, 0, stream>>>(bufA, Wc3, bufB);
    k_gather<1><<<TOTALN / 4, 256, 0, stream>>>(bufB, bufA, rowptr, csr_src, csr_w, dinv, nullptr);
    k_pool<<<NB, 256, 0, stream>>>(bufA, bc3, hg);

    // hypernetwork + compute_q
    k_w1<<<NH * (N_PER / NCH), 256, 0, stream>>>(hg, Wg1, bg1, act, p1);
    k_red1<<<24, 256, 0, stream>>>(p1, h1);
    k_w2<<<NH * Dh, 256, 0, stream>>>(hg, Wg2, bg2, h1, p2);
    k_red2<<<24, 256, 0, stream>>>(p2, h2);
    k_out<<<NB, 192, 0, stream>>>(hg, Wg3, bg3, h2, out);
}

// Round 3
// 440.288 us; speedup vs baseline: 2.4916x; 1.4031x over previous
//
#include <hip/hip_runtime.h>
#include <hip/hip_bf16.h>
#include <math.h>

#define NB 32          // graphs
#define N_PER 1000
#define TOTALN 32000
#define NE 512000
#define HID 128
#define Dh 64
#define NH 3
#define EPSV 1e-6f
#define NCH 8          // n's per k_w1 block
#define PCH 25         // pool chunks per graph (40 nodes each)

__device__ __forceinline__ float softplusf(float x) {
    return fmaxf(x, 0.0f) + log1pf(expf(-fabsf(x)));
}

__global__ __launch_bounds__(256) void k_init_deg(float* deg) {
    int i = blockIdx.x * 256 + threadIdx.x;
    if (i < TOTALN) deg[i] = 1.0f;   // self loop
}

__global__ __launch_bounds__(256) void k_deg(const int* __restrict__ ei, float* deg) {
    int e = blockIdx.x * 256 + threadIdx.x;
    if (e < NE) atomicAdd(&deg[ei[NE + e]], 1.0f);
}

// dinv = rsqrt(deg); cnt = (int)deg - 1 (edges only, self-loop excluded)
__global__ __launch_bounds__(256) void k_prep(float* __restrict__ d, int* __restrict__ cnt) {
    int i = blockIdx.x * 256 + threadIdx.x;
    if (i < TOTALN) {
        float v = d[i];
        cnt[i] = (int)v - 1;
        d[i] = rsqrtf(v);
    }
}

// exclusive scan of cnt[32000] -> rowptr; 125 blocks x 256
__global__ __launch_bounds__(256) void k_scan_block(const int* __restrict__ cnt,
                                                    int* __restrict__ rowptr,
                                                    int* __restrict__ bsum) {
    __shared__ int sh[256];
    int t = threadIdx.x;
    int i = blockIdx.x * 256 + t;
    int v = cnt[i];
    sh[t] = v;
    __syncthreads();
    for (int off = 1; off < 256; off <<= 1) {
        int add = (t >= off) ? sh[t - off] : 0;
        __syncthreads();
        sh[t] += add;
        __syncthreads();
    }
    rowptr[i] = sh[t] - v;   // exclusive within block
    if (t == 255) bsum[blockIdx.x] = sh[255];
}

__global__ void k_scan_tot(int* __restrict__ bsum) {
    if (threadIdx.x == 0) {
        int run = 0;
        for (int i = 0; i < 125; ++i) { int t = bsum[i]; bsum[i] = run; run += t; }
    }
}

__global__ __launch_bounds__(256) void k_scan_add(int* __restrict__ rowptr,
                                                  const int* __restrict__ bsum,
                                                  int* __restrict__ cursor) {
    int i = blockIdx.x * 256 + threadIdx.x;
    int v = rowptr[i] + bsum[blockIdx.x];
    rowptr[i] = v;
    cursor[i] = v;
    if (i == 0) rowptr[TOTALN] = NE;
}

__global__ __launch_bounds__(256) void k_fill(const int* __restrict__ ei,
                                              const float* __restrict__ dinv,
                                              int* __restrict__ cursor,
                                              int* __restrict__ csr_src,
                                              float* __restrict__ csr_w) {
    int e = blockIdx.x * 256 + threadIdx.x;
    if (e < NE) {
        int s = ei[e], d = ei[NE + e];
        int pos = atomicAdd(&cursor[d], 1);
        csr_src[pos] = s;
        csr_w[pos] = dinv[s] * dinv[d];
    }
}

// Y[rows x 128] = X[rows x 128] @ W[128 x 128]; 64 rows per block
__global__ __launch_bounds__(256) void k_mm128(const float* __restrict__ X,
                                               const float* __restrict__ W,
                                               float* __restrict__ Y) {
    __shared__ float xs[64][128];
    __shared__ float ws[32][128];
    int tid = threadIdx.x;
    int row0 = blockIdx.x * 64;
    int c = tid & 127, rp = tid >> 7;
    for (int i = 0; i < 32; ++i) {
        int idx = tid + i * 256;
        xs[idx >> 7][idx & 127] = X[(row0 + (idx >> 7)) * 128 + (idx & 127)];
    }
    float acc[32];
#pragma unroll
    for (int i = 0; i < 32; ++i) acc[i] = 0.f;
    for (int kc = 0; kc < 4; ++kc) {
        __syncthreads();
        for (int i = 0; i < 16; ++i) {
            int idx = tid + i * 256;
            ws[idx >> 7][idx & 127] = W[(kc * 32 + (idx >> 7)) * 128 + (idx & 127)];
        }
        __syncthreads();
#pragma unroll 4
        for (int k = 0; k < 32; ++k) {
            float w = ws[k][c];
#pragma unroll
            for (int i = 0; i < 32; ++i)
                acc[i] += xs[rp * 32 + i][kc * 32 + k] * w;
        }
    }
#pragma unroll
    for (int i = 0; i < 32; ++i)
        Y[(row0 + rp * 32 + i) * 128 + c] = acc[i];
}

// CSR gather: 1 wave per node, float2 per lane, 4-deep edge ILP.
// MODE 0: +bias,relu ; MODE 1: plain
template<int MODE>
__global__ __launch_bounds__(256) void k_gather(const float* __restrict__ feat,
                                                float* __restrict__ out,
                                                const int* __restrict__ rowptr,
                                                const int* __restrict__ csr_src,
                                                const float* __restrict__ csr_w,
                                                const float* __restrict__ dinv,
                                                const float* __restrict__ bias) {
    int wid = threadIdx.x >> 6, lane = threadIdx.x & 63;
    int v = blockIdx.x * 4 + wid;
    const float2* f2 = (const float2*)feat;
    float dv = dinv[v];
    float2 self = f2[v * 64 + lane];
    float acc0 = self.x * dv * dv, acc1 = self.y * dv * dv;
    int e = rowptr[v], e1 = rowptr[v + 1];
    for (; e + 4 <= e1; e += 4) {
        int s0 = csr_src[e], s1 = csr_src[e + 1], s2 = csr_src[e + 2], s3 = csr_src[e + 3];
        float w0 = csr_w[e], w1 = csr_w[e + 1], w2 = csr_w[e + 2], w3 = csr_w[e + 3];
        float2 f0 = f2[s0 * 64 + lane];
        float2 f1 = f2[s1 * 64 + lane];
        float2 fa = f2[s2 * 64 + lane];
        float2 fb = f2[s3 * 64 + lane];
        acc0 += f0.x * w0 + f1.x * w1 + fa.x * w2 + fb.x * w3;
        acc1 += f0.y * w0 + f1.y * w1 + fa.y * w2 + fb.y * w3;
    }
    for (; e < e1; ++e) {
        int s = csr_src[e];
        float w = csr_w[e];
        float2 f = f2[s * 64 + lane];
        acc0 += f.x * w;
        acc1 += f.y * w;
    }
    if (MODE == 0) {
        int c = lane * 2;
        acc0 = fmaxf(acc0 + bias[c], 0.f);
        acc1 = fmaxf(acc1 + bias[c + 1], 0.f);
    }
    ((float2*)out)[v * 64 + lane] = make_float2(acc0, acc1);
}

// pool stage 1: block = (graph b, chunk of 40 nodes) -> partial sums
__global__ __launch_bounds__(256) void k_pool1(const float* __restrict__ A,
                                               float* __restrict__ pp) {
    __shared__ float sh[256];
    int b = blockIdx.x / PCH, ch = blockIdx.x % PCH;
    int c = threadIdx.x & 127, half = threadIdx.x >> 7;
    float acc = 0.f;
    int n0 = ch * 40;
#pragma unroll 4
    for (int j = half; j < 40; j += 2)
        acc += A[(b * N_PER + n0 + j) * 128 + c];
    sh[threadIdx.x] = acc;
    __syncthreads();
    if (threadIdx.x < 128)
        pp[blockIdx.x * 128 + c] = sh[c] + sh[128 + c];
}

// pool stage 2: reduce 25 partials, apply mean + layer-3 bias
__global__ __launch_bounds__(256) void k_pool2(const float* __restrict__ pp,
                                               const float* __restrict__ bias,
                                               float* __restrict__ hg) {
    int i = blockIdx.x * 256 + threadIdx.x;   // b*128 + c
    if (i >= NB * 128) return;
    int b = i >> 7, c = i & 127;
    float s = 0.f;
#pragma unroll
    for (int ch = 0; ch < PCH; ++ch)
        s += pp[(b * PCH + ch) * 128 + c];
    hg[i] = s * (1.0f / N_PER) + bias[c];
}

// block = (head h, chunk of 8 n's); streams Wg1 once; partials p1[chunk][h][b][d]
__global__ __launch_bounds__(256) void k_w1(const float* __restrict__ hg,
                                            const float* __restrict__ Wg1,
                                            const float* __restrict__ bg1,
                                            const float* __restrict__ actions,
                                            float* __restrict__ p1) {
    __shared__ float hgs[32][128];
    __shared__ float wt[128][64];
    __shared__ float act[32];
    int h = blockIdx.x / 125;
    int chunk = blockIdx.x % 125;
    int tid = threadIdx.x;
    for (int i = 0; i < 16; ++i) {
        int idx = tid + i * 256;
        hgs[idx >> 7][idx & 127] = hg[idx];
    }
    int d = tid & 63, bq = tid >> 6;
    float acc[8];
#pragma unroll
    for (int i = 0; i < 8; ++i) acc[i] = 0.f;
    for (int j = 0; j < NCH; ++j) {
        int n = chunk * NCH + j;
        long base = (long)(h * N_PER + n) * Dh;
        __syncthreads();
        for (int i = 0; i < 32; ++i) {
            int idx = tid + i * 256;
            wt[idx >> 6][idx & 63] = Wg1[(long)(idx >> 6) * (NH * N_PER * Dh) + base + (idx & 63)];
        }
        if (tid < 32) act[tid] = actions[tid * N_PER + n];
        __syncthreads();
        float bgv = bg1[base + d];
        float dot[8];
#pragma unroll
        for (int bi = 0; bi < 8; ++bi) dot[bi] = 0.f;
        for (int k = 0; k < 128; ++k) {
            float w = wt[k][d];
#pragma unroll
            for (int bi = 0; bi < 8; ++bi)
                dot[bi] += hgs[bq * 8 + bi][k] * w;
        }
#pragma unroll
        for (int bi = 0; bi < 8; ++bi)
            acc[bi] += act[bq * 8 + bi] * softplusf(dot[bi] + bgv);
    }
    float* po = p1 + (long)(chunk * NH + h) * (32 * 64);
#pragma unroll
    for (int bi = 0; bi < 8; ++bi)
        po[(bq * 8 + bi) * 64 + d] = acc[bi];
}

__global__ __launch_bounds__(256) void k_red1(const float* __restrict__ p1,
                                              float* __restrict__ h1) {
    int o = blockIdx.x * 256 + threadIdx.x;  // b*192 + h*64 + d
    if (o >= 32 * 192) return;
    int bh = o >> 6;
    int h = bh % 3, b = bh / 3;
    int d = o & 63;
    float s = 0.f;
    for (int ch = 0; ch < 125; ++ch)
        s += p1[(ch * 3 + h) * 2048 + b * 64 + d];
    h1[o] = sqrtf(fmaxf(s, 0.f) + EPSV);   // SafeSqrt
}

// block = (h*64+d); writes p2[hd][b][e]
__global__ __launch_bounds__(256) void k_w2(const float* __restrict__ hg,
                                            const float* __restrict__ Wg2,
                                            const float* __restrict__ bg2,
                                            const float* __restrict__ h1,
                                            float* __restrict__ p2) {
    __shared__ float hgs[32][128];
    __shared__ float wt[128][64];
    __shared__ float h1s[32];
    int hd = blockIdx.x;  // h*64 + d
    int tid = threadIdx.x;
    for (int i = 0; i < 16; ++i) {
        int idx = tid + i * 256;
        hgs[idx >> 7][idx & 127] = hg[idx];
    }
    long base = (long)hd * 64;
    for (int i = 0; i < 32; ++i) {
        int idx = tid + i * 256;
        wt[idx >> 6][idx & 63] = Wg2[(long)(idx >> 6) * (NH * Dh * Dh) + base + (idx & 63)];
    }
    int h = hd >> 6, d = hd & 63;
    if (tid < 32) h1s[tid] = h1[tid * (NH * Dh) + h * Dh + d];
    __syncthreads();
    int e = tid & 63, bq = tid >> 6;
    float bgv = bg2[base + e];
    float dot[8];
#pragma unroll
    for (int bi = 0; bi < 8; ++bi) dot[bi] = 0.f;
    for (int k = 0; k < 128; ++k) {
        float w = wt[k][e];
#pragma unroll
        for (int bi = 0; bi < 8; ++bi)
            dot[bi] += hgs[bq * 8 + bi][k] * w;
    }
    float* po = p2 + (long)hd * (32 * 64);
#pragma unroll
    for (int bi = 0; bi < 8; ++bi) {
        int b = bq * 8 + bi;
        po[b * 64 + e] = softplusf(dot[bi] + bgv) * h1s[b];
    }
}

__global__ __launch_bounds__(256) void k_red2(const float* __restrict__ p2,
                                              float* __restrict__ h2) {
    int o = blockIdx.x * 256 + threadIdx.x;  // b*192 + h*64 + e
    if (o >= 32 * 192) return;
    int bh = o >> 6;
    int h = bh % 3, b = bh / 3;
    int e = o & 63;
    float s = 0.f;
    for (int d = 0; d < 64; ++d)
        s += p2[(h * 64 + d) * 2048 + b * 64 + e];
    h2[o] = log1pf(fmaxf(s, 0.f));   // SafeLog
}

__global__ __launch_bounds__(192) void k_out(const float* __restrict__ hg,
                                             const float* __restrict__ Wg3,
                                             const float* __restrict__ bg3,
                                             const float* __restrict__ h2,
                                             float* __restrict__ out) {
    __shared__ float hgb[128];
    __shared__ float hres[NH];
    int b = blockIdx.x, tid = threadIdx.x;
    if (tid < 128) hgb[tid] = hg[b * 128 + tid];
    __syncthreads();
    int h = tid / 64, e = tid & 63;
    int c = h * 64 + e;
    float dot = 0.f;
    for (int k = 0; k < 128; ++k)
        dot += hgb[k] * Wg3[k * (NH * Dh) + c];
    float v = softplusf(dot + bg3[c]) * h2[b * 192 + c];
    for (int off = 32; off; off >>= 1)
        v += __shfl_down(v, off, 64);
    if (e == 0) hres[h] = v;
    __syncthreads();
    if (tid == 0) out[b] = fminf(fminf(hres[0], hres[1]), hres[2]);
}

extern "C" void kernel_launch(void* const* d_in, const int* in_sizes, int n_in,
                              void* d_out, int out_size, void* d_ws, size_t ws_size,
                              hipStream_t stream) {
    const float* x   = (const float*)d_in[0];
    const int*   ei  = (const int*)d_in[1];
    const float* act = (const float*)d_in[3];
    const float* Wc1 = (const float*)d_in[4];
    const float* bc1 = (const float*)d_in[5];
    const float* Wc2 = (const float*)d_in[6];
    const float* bc2 = (const float*)d_in[7];
    const float* Wc3 = (const float*)d_in[8];
    const float* bc3 = (const float*)d_in[9];
    const float* Wg1 = (const float*)d_in[10];
    const float* bg1 = (const float*)d_in[11];
    const float* Wg2 = (const float*)d_in[12];
    const float* bg2 = (const float*)d_in[13];
    const float* Wg3 = (const float*)d_in[14];
    const float* bg3 = (const float*)d_in[15];
    float* out = (float*)d_out;

    float* ws   = (float*)d_ws;
    float* dinv = ws;                               // 32000
    float* bufA = dinv + TOTALN;                    // 4.096M
    float* bufB = bufA + (long)TOTALN * 128;        // 4.096M
    float* hg   = bufB + (long)TOTALN * 128;        // 4096
    float* h1   = hg + 32 * 128;                    // 6144
    float* h2   = h1 + 32 * 192;                    // 6144
    float* p1   = h2 + 32 * 192;                    // 768000
    float* p2   = p1 + 125 * 3 * 2048;              // 393216
    float* csr_w = p2 + 3 * 64 * 2048;              // 512000
    float* pp   = csr_w + NE;                       // 102400
    int* cnt    = (int*)(pp + NB * PCH * 128);      // 32000
    int* rowptr = cnt + TOTALN;                     // 32001
    int* cursor = rowptr + TOTALN + 1;              // 32000
    int* bsum   = cursor + TOTALN;                  // 128
    int* csr_src= bsum + 128;                       // 512000  (~45 MB total)

    // degree + norm + CSR build
    k_init_deg<<<(TOTALN + 255) / 256, 256, 0, stream>>>(dinv);
    k_deg<<<NE / 256, 256, 0, stream>>>(ei, dinv);
    k_prep<<<(TOTALN + 255) / 256, 256, 0, stream>>>(dinv, cnt);
    k_scan_block<<<125, 256, 0, stream>>>(cnt, rowptr, bsum);
    k_scan_tot<<<1, 64, 0, stream>>>(bsum);
    k_scan_add<<<125, 256, 0, stream>>>(rowptr, bsum, cursor);
    k_fill<<<NE / 256, 256, 0, stream>>>(ei, dinv, cursor, csr_src, csr_w);

    // layer 1
    k_mm128<<<500, 256, 0, stream>>>(x, Wc1, bufB);
    k_gather<0><<<TOTALN / 4, 256, 0, stream>>>(bufB, bufA, rowptr, csr_src, csr_w, dinv, bc1);
    // layer 2
    k_mm128<<<500, 256, 0, stream>>>(bufA, Wc2, bufB);
    k_gather<0><<<TOTALN / 4, 256, 0, stream>>>(bufB, bufA, rowptr, csr_src, csr_w, dinv, bc2);
    // layer 3 (no relu; bias folded into pool stage 2)
    k_mm128<<<500, 256, 0, stream>>>(bufA, Wc3, bufB);
    k_gather<1><<<TOTALN / 4, 256, 0, stream>>>(bufB, bufA, rowptr, csr_src, csr_w, dinv, nullptr);
    k_pool1<<<NB * PCH, 256, 0, stream>>>(bufA, pp);
    k_pool2<<<(NB * 128 + 255) / 256, 256, 0, stream>>>(pp, bc3, hg);

    // hypernetwork + compute_q
    k_w1<<<NH * (N_PER / NCH), 256, 0, stream>>>(hg, Wg1, bg1, act, p1);
    k_red1<<<24, 256, 0, stream>>>(p1, h1);
    k_w2<<<NH * Dh, 256, 0, stream>>>(hg, Wg2, bg2, h1, p2);
    k_red2<<<24, 256, 0, stream>>>(p2, h2);
    k_out<<<NB, 192, 0, stream>>>(hg, Wg3, bg3, h2, out);
}

// Round 4
// 406.471 us; speedup vs baseline: 2.6989x; 1.0832x over previous
//
#include <hip/hip_runtime.h>
#include <hip/hip_bf16.h>
#include <math.h>

#define NB 32          // graphs
#define N_PER 1000
#define TOTALN 32000
#define NE 512000
#define HID 128
#define Dh 64
#define NH 3
#define EPSV 1e-6f
#define PCH 25         // pool chunks per graph (40 nodes each)
#define W1CH 250       // k_w1 chunks (4 n's each)

__device__ __forceinline__ float softplusf(float x) {
    return fmaxf(x, 0.0f) + log1pf(expf(-fabsf(x)));
}

__global__ __launch_bounds__(256) void k_init_deg(float* deg) {
    int i = blockIdx.x * 256 + threadIdx.x;
    if (i < TOTALN) deg[i] = 1.0f;   // self loop
}

__global__ __launch_bounds__(256) void k_deg(const int* __restrict__ ei, float* deg) {
    int e = blockIdx.x * 256 + threadIdx.x;
    if (e < NE) atomicAdd(&deg[ei[NE + e]], 1.0f);
}

// dinv = rsqrt(deg); cnt = (int)deg - 1 (edges only, self-loop excluded)
__global__ __launch_bounds__(256) void k_prep(float* __restrict__ d, int* __restrict__ cnt) {
    int i = blockIdx.x * 256 + threadIdx.x;
    if (i < TOTALN) {
        float v = d[i];
        cnt[i] = (int)v - 1;
        d[i] = rsqrtf(v);
    }
}

// exclusive scan of cnt[32000] -> rowptr; 125 blocks x 256
__global__ __launch_bounds__(256) void k_scan_block(const int* __restrict__ cnt,
                                                    int* __restrict__ rowptr,
                                                    int* __restrict__ bsum) {
    __shared__ int sh[256];
    int t = threadIdx.x;
    int i = blockIdx.x * 256 + t;
    int v = cnt[i];
    sh[t] = v;
    __syncthreads();
    for (int off = 1; off < 256; off <<= 1) {
        int add = (t >= off) ? sh[t - off] : 0;
        __syncthreads();
        sh[t] += add;
        __syncthreads();
    }
    rowptr[i] = sh[t] - v;   // exclusive within block
    if (t == 255) bsum[blockIdx.x] = sh[255];
}

__global__ void k_scan_tot(int* __restrict__ bsum) {
    if (threadIdx.x == 0) {
        int run = 0;
        for (int i = 0; i < 125; ++i) { int t = bsum[i]; bsum[i] = run; run += t; }
    }
}

__global__ __launch_bounds__(256) void k_scan_add(int* __restrict__ rowptr,
                                                  const int* __restrict__ bsum,
                                                  int* __restrict__ cursor) {
    int i = blockIdx.x * 256 + threadIdx.x;
    int v = rowptr[i] + bsum[blockIdx.x];
    rowptr[i] = v;
    cursor[i] = v;
    if (i == 0) rowptr[TOTALN] = NE;
}

__global__ __launch_bounds__(256) void k_fill(const int* __restrict__ ei,
                                              const float* __restrict__ dinv,
                                              int* __restrict__ cursor,
                                              int* __restrict__ csr_src,
                                              float* __restrict__ csr_w) {
    int e = blockIdx.x * 256 + threadIdx.x;
    if (e < NE) {
        int s = ei[e], d = ei[NE + e];
        int pos = atomicAdd(&cursor[d], 1);
        csr_src[pos] = s;
        csr_w[pos] = dinv[s] * dinv[d];
    }
}

// Y[rows x 128] = X[rows x 128] @ W[128 x 128]; 64 rows per block
__global__ __launch_bounds__(256) void k_mm128(const float* __restrict__ X,
                                               const float* __restrict__ W,
                                               float* __restrict__ Y) {
    __shared__ float xs[64][128];
    __shared__ float ws[32][128];
    int tid = threadIdx.x;
    int row0 = blockIdx.x * 64;
    int c = tid & 127, rp = tid >> 7;
    for (int i = 0; i < 32; ++i) {
        int idx = tid + i * 256;
        xs[idx >> 7][idx & 127] = X[(row0 + (idx >> 7)) * 128 + (idx & 127)];
    }
    float acc[32];
#pragma unroll
    for (int i = 0; i < 32; ++i) acc[i] = 0.f;
    for (int kc = 0; kc < 4; ++kc) {
        __syncthreads();
        for (int i = 0; i < 16; ++i) {
            int idx = tid + i * 256;
            ws[idx >> 7][idx & 127] = W[(kc * 32 + (idx >> 7)) * 128 + (idx & 127)];
        }
        __syncthreads();
#pragma unroll 4
        for (int k = 0; k < 32; ++k) {
            float w = ws[k][c];
#pragma unroll
            for (int i = 0; i < 32; ++i)
                acc[i] += xs[rp * 32 + i][kc * 32 + k] * w;
        }
    }
#pragma unroll
    for (int i = 0; i < 32; ++i)
        Y[(row0 + rp * 32 + i) * 128 + c] = acc[i];
}

// CSR gather: 1 wave per node, float2 per lane, 4-deep edge ILP.
// MODE 0: +bias,relu ; MODE 1: plain
template<int MODE>
__global__ __launch_bounds__(256) void k_gather(const float* __restrict__ feat,
                                                float* __restrict__ out,
                                                const int* __restrict__ rowptr,
                                                const int* __restrict__ csr_src,
                                                const float* __restrict__ csr_w,
                                                const float* __restrict__ dinv,
                                                const float* __restrict__ bias) {
    int wid = threadIdx.x >> 6, lane = threadIdx.x & 63;
    int v = blockIdx.x * 4 + wid;
    const float2* f2 = (const float2*)feat;
    float dv = dinv[v];
    float2 self = f2[v * 64 + lane];
    float acc0 = self.x * dv * dv, acc1 = self.y * dv * dv;
    int e = rowptr[v], e1 = rowptr[v + 1];
    for (; e + 4 <= e1; e += 4) {
        int s0 = csr_src[e], s1 = csr_src[e + 1], s2 = csr_src[e + 2], s3 = csr_src[e + 3];
        float w0 = csr_w[e], w1 = csr_w[e + 1], w2 = csr_w[e + 2], w3 = csr_w[e + 3];
        float2 f0 = f2[s0 * 64 + lane];
        float2 f1 = f2[s1 * 64 + lane];
        float2 fa = f2[s2 * 64 + lane];
        float2 fb = f2[s3 * 64 + lane];
        acc0 += f0.x * w0 + f1.x * w1 + fa.x * w2 + fb.x * w3;
        acc1 += f0.y * w0 + f1.y * w1 + fa.y * w2 + fb.y * w3;
    }
    for (; e < e1; ++e) {
        int s = csr_src[e];
        float w = csr_w[e];
        float2 f = f2[s * 64 + lane];
        acc0 += f.x * w;
        acc1 += f.y * w;
    }
    if (MODE == 0) {
        int c = lane * 2;
        acc0 = fmaxf(acc0 + bias[c], 0.f);
        acc1 = fmaxf(acc1 + bias[c + 1], 0.f);
    }
    ((float2*)out)[v * 64 + lane] = make_float2(acc0, acc1);
}

// pool stage 1: block = (graph b, chunk of 40 nodes) -> partial sums
__global__ __launch_bounds__(256) void k_pool1(const float* __restrict__ A,
                                               float* __restrict__ pp) {
    __shared__ float sh[256];
    int b = blockIdx.x / PCH, ch = blockIdx.x % PCH;
    int c = threadIdx.x & 127, half = threadIdx.x >> 7;
    float acc = 0.f;
    int n0 = ch * 40;
#pragma unroll 4
    for (int j = half; j < 40; j += 2)
        acc += A[(b * N_PER + n0 + j) * 128 + c];
    sh[threadIdx.x] = acc;
    __syncthreads();
    if (threadIdx.x < 128)
        pp[blockIdx.x * 128 + c] = sh[c] + sh[128 + c];
}

// pool stage 2: reduce 25 partials, apply mean + layer-3 bias
__global__ __launch_bounds__(256) void k_pool2(const float* __restrict__ pp,
                                               const float* __restrict__ bias,
                                               float* __restrict__ hg) {
    int i = blockIdx.x * 256 + threadIdx.x;   // b*128 + c
    if (i >= NB * 128) return;
    int b = i >> 7, c = i & 127;
    float s = 0.f;
#pragma unroll
    for (int ch = 0; ch < PCH; ++ch)
        s += pp[(b * PCH + ch) * 128 + c];
    hg[i] = s * (1.0f / N_PER) + bias[c];
}

// k_w1: block = (head h, chunk of 4 n's). wave = one n, lane = d.
// Wg1 read directly (coalesced 1KB/k per block); hg via wave-uniform scalar loads.
// partials p1[chunk][h][b][d] summed over the block's 4 n's via LDS.
__global__ __launch_bounds__(256) void k_w1(const float* __restrict__ hg,
                                            const float* __restrict__ Wg1,
                                            const float* __restrict__ bg1,
                                            const float* __restrict__ actions,
                                            float* __restrict__ p1) {
    __shared__ float red[32][64];
    int h = blockIdx.x / W1CH, chunk = blockIdx.x % W1CH;
    int tid = threadIdx.x;
    int nsub = tid >> 6, d = tid & 63;
    int n = chunk * 4 + nsub;
    const long KS = (long)NH * N_PER * Dh;   // 192000
    long col = (long)(h * N_PER + n) * Dh + d;
    const float* Wp = Wg1 + col;
    float acc[32];
#pragma unroll
    for (int b = 0; b < 32; ++b) acc[b] = 0.f;
    for (int k = 0; k < 128; k += 4) {
        float w0 = Wp[(long)(k + 0) * KS];
        float w1 = Wp[(long)(k + 1) * KS];
        float w2 = Wp[(long)(k + 2) * KS];
        float w3 = Wp[(long)(k + 3) * KS];
#pragma unroll
        for (int b = 0; b < 32; ++b) {
            float4 hv = *(const float4*)(hg + b * 128 + k);   // wave-uniform -> SMEM
            acc[b] = fmaf(hv.x, w0, fmaf(hv.y, w1, fmaf(hv.z, w2, fmaf(hv.w, w3, acc[b]))));
        }
    }
    float bgv = bg1[col];
#pragma unroll
    for (int b = 0; b < 32; ++b)
        acc[b] = actions[b * N_PER + n] * softplusf(acc[b] + bgv);
    // cross-wave accumulate (4 n's) into red[b][d]
    if (nsub == 0) {
#pragma unroll
        for (int b = 0; b < 32; ++b) red[b][d] = acc[b];
    }
    __syncthreads();
#pragma unroll
    for (int w = 1; w < 4; ++w) {
        if (nsub == w) {
#pragma unroll
            for (int b = 0; b < 32; ++b) red[b][d] += acc[b];
        }
        __syncthreads();
    }
    float* po = p1 + (long)(chunk * NH + h) * 2048;
#pragma unroll
    for (int j = 0; j < 8; ++j) {
        int o = j * 256 + tid;
        po[o] = red[o >> 6][o & 63];
    }
}

__global__ __launch_bounds__(256) void k_red1(const float* __restrict__ p1,
                                              float* __restrict__ h1) {
    int o = blockIdx.x * 256 + threadIdx.x;  // b*192 + h*64 + d
    if (o >= 32 * 192) return;
    int bh = o >> 6;
    int h = bh % 3, b = bh / 3;
    int d = o & 63;
    float s = 0.f;
    for (int ch = 0; ch < W1CH; ++ch)
        s += p1[(ch * 3 + h) * 2048 + b * 64 + d];
    h1[o] = sqrtf(fmaxf(s, 0.f) + EPSV);   // SafeSqrt
}

// block = (h*64+d); writes p2[hd][b][e]
__global__ __launch_bounds__(256) void k_w2(const float* __restrict__ hg,
                                            const float* __restrict__ Wg2,
                                            const float* __restrict__ bg2,
                                            const float* __restrict__ h1,
                                            float* __restrict__ p2) {
    __shared__ float hgs[32][128];
    __shared__ float wt[128][64];
    __shared__ float h1s[32];
    int hd = blockIdx.x;  // h*64 + d
    int tid = threadIdx.x;
    for (int i = 0; i < 16; ++i) {
        int idx = tid + i * 256;
        hgs[idx >> 7][idx & 127] = hg[idx];
    }
    long base = (long)hd * 64;
    for (int i = 0; i < 32; ++i) {
        int idx = tid + i * 256;
        wt[idx >> 6][idx & 63] = Wg2[(long)(idx >> 6) * (NH * Dh * Dh) + base + (idx & 63)];
    }
    int h = hd >> 6, d = hd & 63;
    if (tid < 32) h1s[tid] = h1[tid * (NH * Dh) + h * Dh + d];
    __syncthreads();
    int e = tid & 63, bq = tid >> 6;
    float bgv = bg2[base + e];
    float dot[8];
#pragma unroll
    for (int bi = 0; bi < 8; ++bi) dot[bi] = 0.f;
    for (int k = 0; k < 128; ++k) {
        float w = wt[k][e];
#pragma unroll
        for (int bi = 0; bi < 8; ++bi)
            dot[bi] += hgs[bq * 8 + bi][k] * w;
    }
    float* po = p2 + (long)hd * (32 * 64);
#pragma unroll
    for (int bi = 0; bi < 8; ++bi) {
        int b = bq * 8 + bi;
        po[b * 64 + e] = softplusf(dot[bi] + bgv) * h1s[b];
    }
}

__global__ __launch_bounds__(256) void k_red2(const float* __restrict__ p2,
                                              float* __restrict__ h2) {
    int o = blockIdx.x * 256 + threadIdx.x;  // b*192 + h*64 + e
    if (o >= 32 * 192) return;
    int bh = o >> 6;
    int h = bh % 3, b = bh / 3;
    int e = o & 63;
    float s = 0.f;
    for (int d = 0; d < 64; ++d)
        s += p2[(h * 64 + d) * 2048 + b * 64 + e];
    h2[o] = log1pf(fmaxf(s, 0.f));   // SafeLog
}

__global__ __launch_bounds__(192) void k_out(const float* __restrict__ hg,
                                             const float* __restrict__ Wg3,
                                             const float* __restrict__ bg3,
                                             const float* __restrict__ h2,
                                             float* __restrict__ out) {
    __shared__ float hgb[128];
    __shared__ float hres[NH];
    int b = blockIdx.x, tid = threadIdx.x;
    if (tid < 128) hgb[tid] = hg[b * 128 + tid];
    __syncthreads();
    int h = tid / 64, e = tid & 63;
    int c = h * 64 + e;
    float dot = 0.f;
    for (int k = 0; k < 128; ++k)
        dot += hgb[k] * Wg3[k * (NH * Dh) + c];
    float v = softplusf(dot + bg3[c]) * h2[b * 192 + c];
    for (int off = 32; off; off >>= 1)
        v += __shfl_down(v, off, 64);
    if (e == 0) hres[h] = v;
    __syncthreads();
    if (tid == 0) out[b] = fminf(fminf(hres[0], hres[1]), hres[2]);
}

extern "C" void kernel_launch(void* const* d_in, const int* in_sizes, int n_in,
                              void* d_out, int out_size, void* d_ws, size_t ws_size,
                              hipStream_t stream) {
    const float* x   = (const float*)d_in[0];
    const int*   ei  = (const int*)d_in[1];
    const float* act = (const float*)d_in[3];
    const float* Wc1 = (const float*)d_in[4];
    const float* bc1 = (const float*)d_in[5];
    const float* Wc2 = (const float*)d_in[6];
    const float* bc2 = (const float*)d_in[7];
    const float* Wc3 = (const float*)d_in[8];
    const float* bc3 = (const float*)d_in[9];
    const float* Wg1 = (const float*)d_in[10];
    const float* bg1 = (const float*)d_in[11];
    const float* Wg2 = (const float*)d_in[12];
    const float* bg2 = (const float*)d_in[13];
    const float* Wg3 = (const float*)d_in[14];
    const float* bg3 = (const float*)d_in[15];
    float* out = (float*)d_out;

    float* ws   = (float*)d_ws;
    float* dinv = ws;                               // 32000
    float* bufA = dinv + TOTALN;                    // 4.096M
    float* bufB = bufA + (long)TOTALN * 128;        // 4.096M
    float* hg   = bufB + (long)TOTALN * 128;        // 4096
    float* h1   = hg + 32 * 128;                    // 6144
    float* h2   = h1 + 32 * 192;                    // 6144
    float* csr_w = h2 + 32 * 192;                   // 512000
    float* pp   = csr_w + NE;                       // 102400
    int* cnt    = (int*)(pp + NB * PCH * 128);      // 32000
    int* rowptr = cnt + TOTALN;                     // 32001
    int* cursor = rowptr + TOTALN + 1;              // 32000
    int* bsum   = cursor + TOTALN;                  // 128
    int* csr_src= bsum + 128;                       // 512000
    // aliases: bufB free after last gather; bufA free after pool1
    float* p1   = bufB;                             // 250*3*2048 = 1.536M <= 4.096M
    float* p2   = bufA;                             // 64*3*2048  = 393216 <= 4.096M

    // degree + norm + CSR build
    k_init_deg<<<(TOTALN + 255) / 256, 256, 0, stream>>>(dinv);
    k_deg<<<NE / 256, 256, 0, stream>>>(ei, dinv);
    k_prep<<<(TOTALN + 255) / 256, 256, 0, stream>>>(dinv, cnt);
    k_scan_block<<<125, 256, 0, stream>>>(cnt, rowptr, bsum);
    k_scan_tot<<<1, 64, 0, stream>>>(bsum);
    k_scan_add<<<125, 256, 0, stream>>>(rowptr, bsum, cursor);
    k_fill<<<NE / 256, 256, 0, stream>>>(ei, dinv, cursor, csr_src, csr_w);

    // layer 1
    k_mm128<<<500, 256, 0, stream>>>(x, Wc1, bufB);
    k_gather<0><<<TOTALN / 4, 256, 0, stream>>>(bufB, bufA, rowptr, csr_src, csr_w, dinv, bc1);
    // layer 2
    k_mm128<<<500, 256, 0, stream>>>(bufA, Wc2, bufB);
    k_gather<0><<<TOTALN / 4, 256, 0, stream>>>(bufB, bufA, rowptr, csr_src, csr_w, dinv, bc2);
    // layer 3 (no relu; bias folded into pool stage 2)
    k_mm128<<<500, 256, 0, stream>>>(bufA, Wc3, bufB);
    k_gather<1><<<TOTALN / 4, 256, 0, stream>>>(bufB, bufA, rowptr, csr_src, csr_w, dinv, nullptr);
    k_pool1<<<NB * PCH, 256, 0, stream>>>(bufA, pp);
    k_pool2<<<(NB * 128 + 255) / 256, 256, 0, stream>>>(pp, bc3, hg);

    // hypernetwork + compute_q
    k_w1<<<NH * W1CH, 256, 0, stream>>>(hg, Wg1, bg1, act, p1);
    k_red1<<<24, 256, 0, stream>>>(p1, h1);
    k_w2<<<NH * Dh, 256, 0, stream>>>(hg, Wg2, bg2, h1, p2);
    k_red2<<<24, 256, 0, stream>>>(p2, h2);
    k_out<<<NB, 192, 0, stream>>>(hg, Wg3, bg3, h2, out);
}